// Round 4
// baseline (121.305 us; speedup 1.0000x reference)
//
#include <hip/hip_runtime.h>
#include <math.h>

#define HDIM 5
#define GATES 20      // 4*H
#define DDIM 32
#define EDIM 32
#define INDIM 128     // D + 3E
#define VOC 10
#define SPN (3 * VOC * GATES)   // 600 floats: embedding->gate tables (2.4 KB, L1-resident)
#define HH_OFF 1024             // float offset of hh tables in ws (SoA: [2*20][B])

__device__ __forceinline__ float sigmoidf_(float x) {
    // 1/(1+e^-x); rcp(inf)=0 handles saturation
    return __builtin_amdgcn_rcpf(1.0f + __expf(-x));
}
__device__ __forceinline__ float tanhf_(float x) {
    // tanh(x) = 2/(1+e^-2x) - 1
    float e = __expf(-2.0f * x);
    return fmaf(2.0f, __builtin_amdgcn_rcpf(1.0f + e), -1.0f);
}

// One small dispatch: ws[0..600) = emb->gate dot tables (P);
// ws[HH_OFF + (l*20+r)*B + b] = bias + h_l[b] @ W_hh_l^T  (SoA, coalesced).
__global__ __launch_bounds__(256) void precompute_kernel(
    const float* __restrict__ hidden,   // [2,B,H]
    const float* __restrict__ emb,      // [V,E]
    const float* __restrict__ W_ih0,    // [20,128]
    const float* __restrict__ W_hh0, const float* __restrict__ b_ih0,
    const float* __restrict__ b_hh0,
    const float* __restrict__ W_hh1, const float* __restrict__ b_ih1,
    const float* __restrict__ b_hh1,
    float* __restrict__ ws, int B)
{
    int gid = blockIdx.x * 256 + threadIdx.x;
    if (gid < SPN) {
        int s = gid / (VOC * GATES);
        int rem = gid % (VOC * GATES);
        int v = rem / GATES, r = rem % GATES;
        const float4* ev = (const float4*)(emb + v * EDIM);
        const float4* wv = (const float4*)(W_ih0 + r * INDIM + DDIM + s * EDIM);
        float a = 0.0f;
        #pragma unroll
        for (int k = 0; k < EDIM / 4; ++k) {
            float4 e4 = ev[k], w4 = wv[k];
            a = fmaf(e4.x, w4.x, a); a = fmaf(e4.y, w4.y, a);
            a = fmaf(e4.z, w4.z, a); a = fmaf(e4.w, w4.w, a);
        }
        ws[gid] = a;
    }
    if (gid < B) {
        float h0[HDIM], h1v[HDIM];
        #pragma unroll
        for (int h = 0; h < HDIM; ++h) {
            h0[h]  = hidden[(size_t)gid * HDIM + h];
            h1v[h] = hidden[((size_t)B + gid) * HDIM + h];
        }
        #pragma unroll
        for (int r = 0; r < GATES; ++r) {
            float a0 = b_ih0[r] + b_hh0[r];
            float a1 = b_ih1[r] + b_hh1[r];
            #pragma unroll
            for (int h = 0; h < HDIM; ++h) {
                a0 = fmaf(h0[h],  W_hh0[r * HDIM + h], a0);
                a1 = fmaf(h1v[h], W_hh1[r * HDIM + h], a1);
            }
            ws[HH_OFF + (size_t)r * B + gid] = a0;            // SoA, coalesced
            ws[HH_OFF + (size_t)(GATES + r) * B + gid] = a1;
        }
    }
}

// 2D grid: x = b-blocks, y = t. No LDS, no barrier, no integer division.
__global__ __launch_bounds__(256, 4) void decoder_kernel(
    const float* __restrict__ cell,     // [2,B,H]
    const float* __restrict__ dec_x,    // [T,B,D]
    const int*   __restrict__ midc,     // [T,B]
    const int*   __restrict__ ftc,      // [T,B]
    const int*   __restrict__ mfc,      // [T,B]
    const float* __restrict__ W_ih0,    // [20,128] (only cols 0..31 used here)
    const float* __restrict__ W_ih1,    // [20,5]
    const float* __restrict__ ws,       // P tables + hh SoA tables
    float* __restrict__ out,            // [horizon,B,H]
    int B)
{
    const int b = blockIdx.x * 256 + threadIdx.x;
    if (b >= B) return;
    const int t = blockIdx.y;
    const size_t idx = (size_t)t * B + b;

    // ---- issue long-latency loads first: dec_x row (HBM) ----
    const float4* xp = (const float4*)(dec_x + idx * DDIM);
    float4 x[DDIM / 4];
    #pragma unroll
    for (int k = 0; k < DDIM / 4; ++k) x[k] = xp[k];

    // categorical ids (coalesced dwords)
    const int vm = midc[idx], vf = ftc[idx], vmf = mfc[idx];

    // acc = hh0 (SoA: 20 coalesced dword loads, L2-hot)
    float acc[GATES];
    const float* hh0 = ws + HH_OFF;
    #pragma unroll
    for (int r = 0; r < GATES; ++r) acc[r] = hh0[(size_t)r * B + b];

    // acc += embedding->gate table entries (2.4 KB table, L1-resident)
    const float4* P0 = (const float4*)(ws + vm * GATES);
    const float4* P1 = (const float4*)(ws + VOC * GATES + vf * GATES);
    const float4* P2 = (const float4*)(ws + 2 * VOC * GATES + vmf * GATES);
    #pragma unroll
    for (int k = 0; k < 5; ++k) {
        float4 p0 = P0[k], p1 = P1[k], p2 = P2[k];
        acc[4 * k + 0] += p0.x + p1.x + p2.x;
        acc[4 * k + 1] += p0.y + p1.y + p2.y;
        acc[4 * k + 2] += p0.z + p1.z + p2.z;
        acc[4 * k + 3] += p0.w + p1.w + p2.w;
    }

    // acc += dec_x[t,b,:] @ W_ih0[:, :32]^T   (weights wave-uniform -> scalar pipe)
    #pragma unroll
    for (int r = 0; r < GATES; ++r) {
        const float* w = W_ih0 + r * INDIM;
        float a = acc[r];
        #pragma unroll
        for (int k = 0; k < DDIM / 4; ++k) {
            a = fmaf(x[k].x, w[4 * k + 0], a);
            a = fmaf(x[k].y, w[4 * k + 1], a);
            a = fmaf(x[k].z, w[4 * k + 2], a);
            a = fmaf(x[k].w, w[4 * k + 3], a);
        }
        acc[r] = a;
    }

    // layer-0 nonlinearity -> h1
    float h1[HDIM];
    #pragma unroll
    for (int r = 0; r < HDIM; ++r) {
        float c0 = cell[(size_t)b * HDIM + r];
        float ii = sigmoidf_(acc[r]);
        float ff = sigmoidf_(acc[HDIM + r]);
        float gg = tanhf_(acc[2 * HDIM + r]);
        float oo = sigmoidf_(acc[3 * HDIM + r]);
        float cn = fmaf(ff, c0, ii * gg);
        h1[r] = oo * tanhf_(cn);
    }

    // layer-1 gates: g1 = hh1 (SoA coalesced) + h1 @ W_ih1^T (scalar weights)
    float g1[GATES];
    const float* hh1 = ws + HH_OFF + (size_t)GATES * B;
    #pragma unroll
    for (int r = 0; r < GATES; ++r) {
        float a = hh1[(size_t)r * B + b];
        #pragma unroll
        for (int h = 0; h < HDIM; ++h)
            a = fmaf(h1[h], W_ih1[r * HDIM + h], a);
        g1[r] = a;
    }

    // layer-1 nonlinearity -> out
    #pragma unroll
    for (int r = 0; r < HDIM; ++r) {
        float c1 = cell[((size_t)B + b) * HDIM + r];
        float ii = sigmoidf_(g1[r]);
        float ff = sigmoidf_(g1[HDIM + r]);
        float gg = tanhf_(g1[2 * HDIM + r]);
        float oo = sigmoidf_(g1[3 * HDIM + r]);
        float cn = fmaf(ff, c1, ii * gg);
        out[idx * HDIM + r] = oo * tanhf_(cn);
    }
}

extern "C" void kernel_launch(void* const* d_in, const int* in_sizes, int n_in,
                              void* d_out, int out_size, void* d_ws, size_t ws_size,
                              hipStream_t stream) {
    // dict order: horizon, hidden, cell, dec_x, mote_id_cat, fault_type_cat,
    // mote_fault_cat, mote_embed, W_ih0, W_hh0, b_ih0, b_hh0, W_ih1, W_hh1, b_ih1, b_hh1
    const float* hidden = (const float*)d_in[1];
    const float* cellp  = (const float*)d_in[2];
    const float* dec_x  = (const float*)d_in[3];
    const int*   midc   = (const int*)d_in[4];
    const int*   ftc    = (const int*)d_in[5];
    const int*   mfc    = (const int*)d_in[6];
    const float* emb    = (const float*)d_in[7];
    const float* W_ih0  = (const float*)d_in[8];
    const float* W_hh0  = (const float*)d_in[9];
    const float* b_ih0  = (const float*)d_in[10];
    const float* b_hh0  = (const float*)d_in[11];
    const float* W_ih1  = (const float*)d_in[12];
    const float* W_hh1  = (const float*)d_in[13];
    const float* b_ih1  = (const float*)d_in[14];
    const float* b_hh1  = (const float*)d_in[15];
    float* out = (float*)d_out;
    float* ws  = (float*)d_ws;

    int B = in_sizes[1] / (2 * HDIM);        // hidden is [2,B,H]
    int horizon = out_size / (B * HDIM);     // out is [horizon,B,H]

    int pre_n = (B > SPN ? B : SPN);
    int pre_grid = (pre_n + 255) / 256;
    precompute_kernel<<<pre_grid, 256, 0, stream>>>(
        hidden, emb, W_ih0, W_hh0, b_ih0, b_hh0, W_hh1, b_ih1, b_hh1, ws, B);

    dim3 grid((B + 255) / 256, horizon, 1);
    decoder_kernel<<<grid, 256, 0, stream>>>(
        cellp, dec_x, midc, ftc, mfc, W_ih0, W_ih1, ws, out, B);
}

// Round 5
// 121.129 us; speedup vs baseline: 1.0015x; 1.0015x over previous
//
#include <hip/hip_runtime.h>
#include <math.h>

#define HDIM 5
#define GATES 20      // 4*H
#define DDIM 32
#define EDIM 32
#define INDIM 128     // D + 3E
#define VOC 10
#define SPN (3 * VOC * GATES)   // 600 floats: embedding->gate tables
#define HH_OFF 1024             // ws float offset: hh SoA tables [2*20][B]
// cell SoA tables [2*5][B] follow hh
#define ROWF4 9                 // LDS staging row stride in float4 (144B: pads bank quads)

__device__ __forceinline__ float sigmoidf_(float x) {
    return __builtin_amdgcn_rcpf(1.0f + __expf(-x));   // rcp(inf)=0 saturates
}
__device__ __forceinline__ float tanhf_(float x) {
    float e = __expf(-2.0f * x);
    return fmaf(2.0f, __builtin_amdgcn_rcpf(1.0f + e), -1.0f);
}

// ws[0..600): P tables. ws[HH_OFF + (l*20+r)*B + b]: bias + h_l[b]@W_hh_l^T (SoA).
// ws[HH_OFF + 40B + (l*5+r)*B + b]: cell transposed (SoA).
__global__ __launch_bounds__(256) void precompute_kernel(
    const float* __restrict__ hidden,   // [2,B,H]
    const float* __restrict__ cell,     // [2,B,H]
    const float* __restrict__ emb,      // [V,E]
    const float* __restrict__ W_ih0,    // [20,128]
    const float* __restrict__ W_hh0, const float* __restrict__ b_ih0,
    const float* __restrict__ b_hh0,
    const float* __restrict__ W_hh1, const float* __restrict__ b_ih1,
    const float* __restrict__ b_hh1,
    float* __restrict__ ws, int B)
{
    int gid = blockIdx.x * 256 + threadIdx.x;
    if (gid < SPN) {
        int s = gid / (VOC * GATES);
        int rem = gid % (VOC * GATES);
        int v = rem / GATES, r = rem % GATES;
        const float4* ev = (const float4*)(emb + v * EDIM);
        const float4* wv = (const float4*)(W_ih0 + r * INDIM + DDIM + s * EDIM);
        float a = 0.0f;
        #pragma unroll
        for (int k = 0; k < EDIM / 4; ++k) {
            float4 e4 = ev[k], w4 = wv[k];
            a = fmaf(e4.x, w4.x, a); a = fmaf(e4.y, w4.y, a);
            a = fmaf(e4.z, w4.z, a); a = fmaf(e4.w, w4.w, a);
        }
        ws[gid] = a;
    }
    if (gid < B) {
        float h0[HDIM], h1v[HDIM];
        #pragma unroll
        for (int h = 0; h < HDIM; ++h) {
            h0[h]  = hidden[(size_t)gid * HDIM + h];
            h1v[h] = hidden[((size_t)B + gid) * HDIM + h];
        }
        #pragma unroll
        for (int r = 0; r < GATES; ++r) {
            float a0 = b_ih0[r] + b_hh0[r];
            float a1 = b_ih1[r] + b_hh1[r];
            #pragma unroll
            for (int h = 0; h < HDIM; ++h) {
                a0 = fmaf(h0[h],  W_hh0[r * HDIM + h], a0);
                a1 = fmaf(h1v[h], W_hh1[r * HDIM + h], a1);
            }
            ws[HH_OFF + (size_t)r * B + gid] = a0;
            ws[HH_OFF + (size_t)(GATES + r) * B + gid] = a1;
        }
        float* ct = ws + HH_OFF + (size_t)(2 * GATES) * B;
        #pragma unroll
        for (int r = 0; r < 2 * HDIM; ++r) {
            // cell[l][b][r] -> ct[(l*5+r)][b]
            int l = r / HDIM, rr = r % HDIM;
            ct[(size_t)r * B + gid] = cell[((size_t)l * B + gid) * HDIM + rr];
        }
    }
}

// 2D grid: x = b-blocks, y = t. dec_x staged through LDS (coalesced global,
// bank-floor LDS); outputs transposed through LDS for coalesced stores.
__global__ __launch_bounds__(256, 4) void decoder_kernel(
    const float* __restrict__ dec_x,    // [T,B,D]
    const int*   __restrict__ midc,     // [T,B]
    const int*   __restrict__ ftc,      // [T,B]
    const int*   __restrict__ mfc,      // [T,B]
    const float* __restrict__ W_ih0,    // [20,128] (cols 0..31 used)
    const float* __restrict__ W_ih1,    // [20,5]
    const float* __restrict__ ws,       // P + hh SoA + cell SoA
    float* __restrict__ out,            // [horizon,B,H]
    int B)
{
    __shared__ float4 sX[256 * ROWF4];  // 36,864 B staging (reused for out)
    __shared__ float  sP[SPN];          // 2,400 B

    const int tid = threadIdx.x;
    const int b0  = blockIdx.x * 256;
    const int b   = b0 + tid;
    const int t   = blockIdx.y;
    const bool valid = (b < B);
    const int nb = (B - b0 < 256) ? (B - b0) : 256;   // valid rows in this block

    for (int j = tid; j < SPN; j += 256) sP[j] = ws[j];

    // ---- stage dec_x block slice: 2048 float4, fully coalesced ----
    const float4* gx = (const float4*)(dec_x + ((size_t)t * B + b0) * DDIM);
    #pragma unroll
    for (int j = 0; j < 8; ++j) {
        int i = tid + 256 * j;          // flat float4 index in block slice
        int row = i >> 3, col = i & 7;
        if (row < nb) sX[row * ROWF4 + col] = gx[i];
    }
    __syncthreads();

    float4 x[DDIM / 4];
    #pragma unroll
    for (int k = 0; k < DDIM / 4; ++k) x[k] = sX[tid * ROWF4 + k];

    float h2[HDIM];
    if (valid) {
        const size_t idx = (size_t)t * B + b;
        const int vm = midc[idx], vf = ftc[idx], vmf = mfc[idx];

        // acc = hh0[b] (SoA coalesced) + P gathers (LDS)
        float acc[GATES];
        const float* hh0 = ws + HH_OFF;
        #pragma unroll
        for (int r = 0; r < GATES; ++r) acc[r] = hh0[(size_t)r * B + b];

        const float4* P0 = (const float4*)(sP + vm * GATES);
        const float4* P1 = (const float4*)(sP + VOC * GATES + vf * GATES);
        const float4* P2 = (const float4*)(sP + 2 * VOC * GATES + vmf * GATES);
        #pragma unroll
        for (int k = 0; k < 5; ++k) {
            float4 p0 = P0[k], p1 = P1[k], p2 = P2[k];
            acc[4 * k + 0] += p0.x + p1.x + p2.x;
            acc[4 * k + 1] += p0.y + p1.y + p2.y;
            acc[4 * k + 2] += p0.z + p1.z + p2.z;
            acc[4 * k + 3] += p0.w + p1.w + p2.w;
        }

        // acc += x @ W_ih0[:, :32]^T  (weights wave-uniform -> scalar pipe)
        #pragma unroll
        for (int r = 0; r < GATES; ++r) {
            const float* w = W_ih0 + r * INDIM;
            float a = acc[r];
            #pragma unroll
            for (int k = 0; k < DDIM / 4; ++k) {
                a = fmaf(x[k].x, w[4 * k + 0], a);
                a = fmaf(x[k].y, w[4 * k + 1], a);
                a = fmaf(x[k].z, w[4 * k + 2], a);
                a = fmaf(x[k].w, w[4 * k + 3], a);
            }
            acc[r] = a;
        }

        // layer-0 nonlinearity -> h1 (cell SoA coalesced)
        const float* ct = ws + HH_OFF + (size_t)(2 * GATES) * B;
        float h1[HDIM];
        #pragma unroll
        for (int r = 0; r < HDIM; ++r) {
            float c0 = ct[(size_t)r * B + b];
            float ii = sigmoidf_(acc[r]);
            float ff = sigmoidf_(acc[HDIM + r]);
            float gg = tanhf_(acc[2 * HDIM + r]);
            float oo = sigmoidf_(acc[3 * HDIM + r]);
            float cn = fmaf(ff, c0, ii * gg);
            h1[r] = oo * tanhf_(cn);
        }

        // layer-1 gates: hh1 SoA + h1 @ W_ih1^T
        float g1[GATES];
        const float* hh1 = ws + HH_OFF + (size_t)GATES * B;
        #pragma unroll
        for (int r = 0; r < GATES; ++r) {
            float a = hh1[(size_t)r * B + b];
            #pragma unroll
            for (int h = 0; h < HDIM; ++h)
                a = fmaf(h1[h], W_ih1[r * HDIM + h], a);
            g1[r] = a;
        }

        // layer-1 nonlinearity -> h2
        #pragma unroll
        for (int r = 0; r < HDIM; ++r) {
            float c1 = ct[(size_t)(HDIM + r) * B + b];
            float ii = sigmoidf_(g1[r]);
            float ff = sigmoidf_(g1[HDIM + r]);
            float gg = tanhf_(g1[2 * HDIM + r]);
            float oo = sigmoidf_(g1[3 * HDIM + r]);
            float cn = fmaf(ff, c1, ii * gg);
            h2[r] = oo * tanhf_(cn);
        }
    }

    // ---- transpose outputs through LDS for coalesced stores ----
    __syncthreads();                    // everyone done reading sX
    float* sOut = (float*)sX;           // reuse staging buffer (need 5 KB)
    if (valid) {
        #pragma unroll
        for (int r = 0; r < HDIM; ++r) sOut[tid * HDIM + r] = h2[r];
    }
    __syncthreads();
    float* gout = out + ((size_t)t * B + b0) * HDIM;
    const int cnt = nb * HDIM;          // contiguous floats this block owns
    #pragma unroll
    for (int j = 0; j < HDIM; ++j) {
        int i = j * 256 + tid;
        if (i < cnt) gout[i] = sOut[i];
    }
}

extern "C" void kernel_launch(void* const* d_in, const int* in_sizes, int n_in,
                              void* d_out, int out_size, void* d_ws, size_t ws_size,
                              hipStream_t stream) {
    // dict order: horizon, hidden, cell, dec_x, mote_id_cat, fault_type_cat,
    // mote_fault_cat, mote_embed, W_ih0, W_hh0, b_ih0, b_hh0, W_ih1, W_hh1, b_ih1, b_hh1
    const float* hidden = (const float*)d_in[1];
    const float* cellp  = (const float*)d_in[2];
    const float* dec_x  = (const float*)d_in[3];
    const int*   midc   = (const int*)d_in[4];
    const int*   ftc    = (const int*)d_in[5];
    const int*   mfc    = (const int*)d_in[6];
    const float* emb    = (const float*)d_in[7];
    const float* W_ih0  = (const float*)d_in[8];
    const float* W_hh0  = (const float*)d_in[9];
    const float* b_ih0  = (const float*)d_in[10];
    const float* b_hh0  = (const float*)d_in[11];
    const float* W_ih1  = (const float*)d_in[12];
    const float* W_hh1  = (const float*)d_in[13];
    const float* b_ih1  = (const float*)d_in[14];
    const float* b_hh1  = (const float*)d_in[15];
    float* out = (float*)d_out;
    float* ws  = (float*)d_ws;

    int B = in_sizes[1] / (2 * HDIM);        // hidden is [2,B,H]
    int horizon = out_size / (B * HDIM);     // out is [horizon,B,H]

    int pre_n = (B > SPN ? B : SPN);
    int pre_grid = (pre_n + 255) / 256;
    precompute_kernel<<<pre_grid, 256, 0, stream>>>(
        hidden, cellp, emb, W_ih0, W_hh0, b_ih0, b_hh0, W_hh1, b_ih1, b_hh1,
        ws, B);

    dim3 grid((B + 255) / 256, horizon, 1);
    decoder_kernel<<<grid, 256, 0, stream>>>(
        dec_x, midc, ftc, mfc, W_ih0, W_ih1, ws, out, B);
}